// Round 6
// baseline (1595.360 us; speedup 1.0000x reference)
//
#include <hip/hip_runtime.h>

// Problem constants (from reference)
#define ARW_N_NODES   100000
#define ARW_N_EDGES   3200000
#define ARW_N_WALKERS 400000            // NUM_NODES * WALKS_PER_NODE
#define ARW_WLEN      8                 // WALK_LENGTH
#define ARW_LOUT      7                 // WALK_LENGTH - 1 (SKIP_FIRST)
#define ARW_ROW_LEN   6000000           // N_EDGES + N_WALKERS*LOUT
#define ARW_OUT_ELEMS 18000000          // 3 * ROW_LEN (FLOAT32! 72 MB)

// d_out is FLOAT32 (output tuple is (int32, float32) -> "else float*" rule):
//   f32 [0, 6M)    out_edge_index row0: [0,3.2M) originals, [3.2M,6M) roots
//   f32 [6M, 12M)  out_edge_index row1: [6M,9.2M) originals, [9.2M,12M) targets
//   f32 [12M, 18M) out_edge_weight:     [12M,15.2M) originals, [15.2M,18M) ones
//
// Scratch = int32 view of d_out, staged lifetimes (all dead before overwrite):
//   deg/cur/rowptr/bsum @ [6.0M, 6.33M)   (row1-originals region; dead at assemble)
//   eid               @ [7.0M, 10.2M)     (row1 region; dead after rank_k)
//   col_s             @ [12M, 15.2M)      (weights region; dead after walk_k)
// walk_k writes f32 targets @ [9.2M,12M) AFTER rank_k (eid dead). assemble_k
// (last) writes everything else, clobbering only dead scratch.
#define ARW_DEG   6000000
#define ARW_CUR   6100000
#define ARW_RP    6200000
#define ARW_BSUM  6320000
#define ARW_EID   7000000
#define ARW_COLS  12000000
#define ARW_NBLK  391                   // ceil(N_NODES/256)
#define ARW_ZCNT  320791                // [ARW_DEG, ARW_BSUM+391) zeroed

// Template-named symbol kept in case the harness resolves kernels by name.
__global__ void AddRandomWalkEdge_16896401342869_kernel() {}

// ---------- dtype detectors (statistical, 64 words; error prob ~0) ----------
static __device__ __forceinline__ int arw16896_is_f32(const unsigned int* w) {
    // f32 U[0,1): bits[14:7] ~uniform -> ~4/64 in [0x70,0x80). bf16 pair: ~64/64.
    int structured = 0;
    for (int k = 0; k < 64; k++) {
        unsigned int e = (w[k] >> 7) & 0xFFu;
        structured += (e >= 0x70u && e < 0x80u) ? 1 : 0;
    }
    return structured < 32;
}
static __device__ __forceinline__ int arw16896_is_i64(const unsigned int* w) {
    int zeros = 0;                      // i64 node ids: high words all zero
    for (int k = 0; k < 64; k++) zeros += (w[k] == 0u) ? 1 : 0;
    return zeros >= 16;
}
static __device__ __forceinline__ float arw16896_ldf(const void* p, int i, int f32) {
    if (f32) return ((const float*)p)[i];
    unsigned int u = ((unsigned int)((const unsigned short*)p)[i]) << 16;
    return __uint_as_float(u);
}
static __device__ __forceinline__ int arw16896_ldi(const void* p, int i, int i64) {
    if (i64) return (int)((const long long*)p)[i];
    return ((const int*)p)[i];
}
static __device__ __forceinline__ int arw16896_clampn(int v) {
    if (v < 0) return 0;
    if (v >= ARW_N_NODES) return ARW_N_NODES - 1;
    return v;
}

// ---------- 0. zero scratch counters / diag ----------
__global__ void arw16896_zero(int* s) {
    int i = blockIdx.x * blockDim.x + threadIdx.x;
    if (i < ARW_ZCNT) s[ARW_DEG + i] = 0;
}
__global__ void arw16896_zerows(int* c) {
    if (c != 0 && blockIdx.x == 0 && threadIdx.x < 16) c[threadIdx.x] = 0;
}

// ---------- 1. degree histogram ----------
__global__ void arw16896_hist(const void* ei, int* s) {
    __shared__ int i64f;
    if (threadIdx.x == 0) i64f = arw16896_is_i64((const unsigned int*)ei);
    __syncthreads();
    int e = blockIdx.x * blockDim.x + threadIdx.x;
    if (e < ARW_N_EDGES)
        atomicAdd(&s[ARW_DEG + arw16896_clampn(arw16896_ldi(ei, e, i64f))], 1);
}

// ---------- 2a. per-chunk sums ----------
__global__ void arw16896_bsum(int* s) {
    __shared__ int sm[256];
    int i = blockIdx.x * 256 + (int)threadIdx.x;
    sm[threadIdx.x] = (i < ARW_N_NODES) ? s[ARW_DEG + i] : 0;
    __syncthreads();
    for (int off = 128; off > 0; off >>= 1) {
        if ((int)threadIdx.x < off) sm[threadIdx.x] += sm[threadIdx.x + off];
        __syncthreads();
    }
    if (threadIdx.x == 0) s[ARW_BSUM + blockIdx.x] = sm[0];
}
// ---------- 2b. exclusive scan of chunk sums ----------
__global__ void arw16896_bscan(int* s) {
    if (blockIdx.x == 0 && threadIdx.x == 0) {
        int acc = 0;
        for (int b = 0; b < ARW_NBLK; b++) { int v = s[ARW_BSUM + b]; s[ARW_BSUM + b] = acc; acc += v; }
    }
}
// ---------- 2c. rowptr ----------
__global__ void arw16896_scan(int* s) {
    __shared__ int sm[256];
    int i = blockIdx.x * 256 + (int)threadIdx.x;
    sm[threadIdx.x] = (i < ARW_N_NODES) ? s[ARW_DEG + i] : 0;
    __syncthreads();
    for (int off = 1; off < 256; off <<= 1) {
        int x = 0;
        if ((int)threadIdx.x >= off) x = sm[threadIdx.x - off];
        __syncthreads();
        sm[threadIdx.x] += x;
        __syncthreads();
    }
    if (i < ARW_N_NODES) s[ARW_RP + i + 1] = sm[threadIdx.x] + s[ARW_BSUM + blockIdx.x];
    if (i == 0) s[ARW_RP] = 0;
}

// ---------- 3. scatter edge ids (+ snapshot rowptr total) ----------
__global__ void arw16896_scatter(const void* ei, int* s, int* c) {
    __shared__ int i64f;
    if (threadIdx.x == 0) i64f = arw16896_is_i64((const unsigned int*)ei);
    __syncthreads();
    int e = blockIdx.x * blockDim.x + threadIdx.x;
    if (e == 0 && c != 0) c[4] = s[ARW_RP + ARW_N_NODES];
    if (e < ARW_N_EDGES) {
        int r = arw16896_clampn(arw16896_ldi(ei, e, i64f));
        int slot = atomicAdd(&s[ARW_CUR + r], 1);
        int idx = s[ARW_RP + r] + slot;
        if (idx >= 0 && idx < ARW_N_EDGES) {
            s[ARW_EID + idx] = e;
            if (c != 0) atomicAdd(&c[0], 1);
        }
    }
}

// ---------- 4. stable rank -> col_s ----------
__global__ void arw16896_rank(const void* ei, int* s, int* c) {
    __shared__ int i64f;
    if (threadIdx.x == 0) i64f = arw16896_is_i64((const unsigned int*)ei);
    __syncthreads();
    int i = blockIdx.x * blockDim.x + threadIdx.x;
    if (i < ARW_N_EDGES) {
        int e = s[ARW_EID + i];
        if (e < 0 || e >= ARW_N_EDGES) e = 0;
        int r = arw16896_clampn(arw16896_ldi(ei, e, i64f));
        int base = s[ARW_RP + r];
        int d = s[ARW_DEG + r];
        int rank = 0;
        for (int j = 0; j < d; j++) rank += (s[ARW_EID + base + j] < e) ? 1 : 0;
        int idx = base + rank;
        if (idx >= 0 && idx < ARW_N_EDGES) {
            s[ARW_COLS + idx] = arw16896_clampn(arw16896_ldi(ei, ARW_N_EDGES + e, i64f));
            if (c != 0) atomicAdd(&c[1], 1);
        }
    }
}

// ---------- 5. walks: write FLOAT32 targets @ [9.2M,12M) ----------
__global__ void arw16896_walk(const void* ru, const int* s, float* o, int* c) {
    __shared__ int f32f;
    if (threadIdx.x == 0) f32f = arw16896_is_f32((const unsigned int*)ru);
    __syncthreads();
    int w = blockIdx.x * blockDim.x + threadIdx.x;
    if (w >= ARW_N_WALKERS) return;
    int cur = w % ARW_N_NODES;               // start = tile(arange(N), WALKS)
    for (int t = 0; t < ARW_WLEN; t++) {
        float u = arw16896_ldf(ru, w * ARW_WLEN + t, f32f);
        int d = s[ARW_DEG + cur];
        if (d > 0) {
            int off = (int)(u * (float)d);   // f32 mul + trunc (matches reference)
            if (off < 0) off = 0;
            if (off > d - 1) off = d - 1;    // reference clamp
            int idx = s[ARW_RP + cur] + off;
            if (idx < 0) idx = 0;
            if (idx >= ARW_N_EDGES) idx = ARW_N_EDGES - 1;
            cur = arw16896_clampn(s[ARW_COLS + idx]);
        }
        if (t >= 1)
            o[ARW_ROW_LEN + ARW_N_EDGES + w * ARW_LOUT + (t - 1)] = (float)cur;
    }
    if (c != 0) atomicAdd(&c[2], 1);
}

// ---------- 6. final assembly (FLOAT32 everywhere) ----------
__global__ void arw16896_assemble(const void* ei, const void* wgt, float* o) {
    __shared__ int i64f, wf32;
    if (threadIdx.x == 0) {
        i64f = arw16896_is_i64((const unsigned int*)ei);
        wf32 = arw16896_is_f32((const unsigned int*)wgt);
    }
    __syncthreads();
    int i = blockIdx.x * blockDim.x + threadIdx.x;
    if (i < ARW_N_EDGES) {
        float r0 = (float)arw16896_ldi(ei, i, i64f);
        float r1 = (float)arw16896_ldi(ei, ARW_N_EDGES + i, i64f);
        float ww = arw16896_ldf(wgt, i, wf32);
        o[2 * ARW_ROW_LEN + i] = ww;         // weights  (clobbers dead col_s)
        o[ARW_ROW_LEN + i]     = r1;         // row1 originals (clobbers dead deg/..../eid)
        o[i]                   = r0;         // row0 originals
    }
    if (i < ARW_N_WALKERS * ARW_LOUT) {
        int w = i / ARW_LOUT;
        o[ARW_N_EDGES + i]                   = (float)(w % ARW_N_NODES);  // roots
        o[2 * ARW_ROW_LEN + ARW_N_EDGES + i] = 1.0f;                      // ones
    }
}

// ---------- 7. invariant check -> decodable float sentinel at a ref==0 slot ----------
// flags: b0 rowptr-total  b1 scatter-cnt  b2 rank-cnt  b3 walk-cnt  b4 host-size
__global__ void arw16896_check(const int* c, float* o, int hflags) {
    if (threadIdx.x != 0 || blockIdx.x != 0) return;
    int flags = 0;
    if (c != 0) {
        if (c[4] != ARW_N_EDGES)   flags |= 1;
        if (c[0] != ARW_N_EDGES)   flags |= 2;
        if (c[1] != ARW_N_EDGES)   flags |= 4;
        if (c[2] != ARW_N_WALKERS) flags |= 8;
    }
    flags |= (hflags & 1) << 4;
    if (flags != 0)
        o[ARW_N_EDGES] = 262144.0f * (float)(1 + flags);  // walker-0 root slot, ref=0
}

extern "C" void kernel_launch(void* const* d_in, const int* in_sizes, int n_in,
                              void* d_out, int out_size, void* d_ws, size_t ws_size,
                              hipStream_t stream) {
    const void* ei  = d_in[0];                 // [2, N_EDGES] row-major, int
    const void* wgt = d_in[1];                 // [N_EDGES] float
    const void* ru  = d_in[2];                 // [N_WALKERS, WLEN] float, row-major
    int*   s = (int*)d_out;                    // scratch view
    float* o = (float*)d_out;                  // output view (FLOAT32)
    int*   c = (ws_size >= 64) ? (int*)d_ws : (int*)0;
    const int B = 256;

    int hflags = 0;
    if (out_size != ARW_OUT_ELEMS || n_in != 3 ||
        in_sizes[0] != 2 * ARW_N_EDGES || in_sizes[1] != ARW_N_EDGES ||
        in_sizes[2] != ARW_N_WALKERS * ARW_WLEN) hflags = 1;

    arw16896_zero    <<<(ARW_ZCNT + B - 1) / B, B, 0, stream>>>(s);
    arw16896_zerows  <<<1, 64, 0, stream>>>(c);
    arw16896_hist    <<<(ARW_N_EDGES + B - 1) / B, B, 0, stream>>>(ei, s);
    arw16896_bsum    <<<ARW_NBLK, B, 0, stream>>>(s);
    arw16896_bscan   <<<1, 64, 0, stream>>>(s);
    arw16896_scan    <<<ARW_NBLK, B, 0, stream>>>(s);
    arw16896_scatter <<<(ARW_N_EDGES + B - 1) / B, B, 0, stream>>>(ei, s, c);
    arw16896_rank    <<<(ARW_N_EDGES + B - 1) / B, B, 0, stream>>>(ei, s, c);
    arw16896_walk    <<<(ARW_N_WALKERS + B - 1) / B, B, 0, stream>>>(ru, s, o, c);
    arw16896_assemble<<<(ARW_N_EDGES + B - 1) / B, B, 0, stream>>>(ei, wgt, o);
    arw16896_check   <<<1, 64, 0, stream>>>(c, o, hflags);
}

// Round 7
// 519.683 us; speedup vs baseline: 3.0699x; 3.0699x over previous
//
#include <hip/hip_runtime.h>

// Problem constants
#define ARW_N_NODES   100000
#define ARW_N_EDGES   3200000
#define ARW_N_WALKERS 400000
#define ARW_WLEN      8
#define ARW_LOUT      7
#define ARW_ROW_LEN   6000000           // N_EDGES + N_WALKERS*LOUT
#define ARW_OUT_ELEMS 18000000          // float32 output elements

// Sort geometry: 196 buckets of 512 rows (b = r>>9); 3125 tiles of 1024 edges.
#define ARW_NB    196
#define ARW_NT    3125
#define ARW_TILE  1024
#define ARW_SEGCAP 18432               // LDS cap per bucket (mean 16384, sigma ~127)

// Scratch inside d_out (18M floats = 72MB), int32 view; staged lifetimes:
//   Ht  @ [0, 612500)        tile histograms [t][b]      (row0 region, dead by assemble)
//   Bt  @ [700000, 1312500)  scan bases [t][b]; Bt[0*196+b] = bucket start
//   deg @ [1400000, 1500000)
//   rowptr @ [1500000, 1600001)
//   bsum@ [1610000, +391)
//   P   @ [6000000, 9200000) packed partition (row1-orig region, dead after pass2)
//   col_s @ [12000000, 15200000) (weights region; assemble overwrites last)
// walk writes float targets @ [9200000, 12000000).
#define ARW_HT    0
#define ARW_BT    700000
#define ARW_DEG   1400000
#define ARW_RP    1500000
#define ARW_BSUM  1610000
#define ARW_P     6000000
#define ARW_COLS  12000000
#define ARW_NBLK  391                  // ceil(N_NODES/256) for rowptr scan

__global__ void AddRandomWalkEdge_16896401342869_kernel() {}

// ---------- 1. tile histogram over 196 buckets (LDS atomics only) ----------
__global__ __launch_bounds__(1024) void arw16896_thist(const int* __restrict__ row,
                                                       int* __restrict__ s) {
    __shared__ int h[256];
    int tid = threadIdx.x;
    if (tid < 256) h[tid] = 0;
    __syncthreads();
    int e = blockIdx.x * ARW_TILE + tid;
    atomicAdd(&h[row[e] >> 9], 1);
    __syncthreads();
    if (tid < ARW_NB) s[ARW_HT + blockIdx.x * ARW_NB + tid] = h[tid];
}

// ---------- 2. table scan: Bt[t][b] = colBase[b] + sum_{t'<t} Ht[t'][b] ----------
__global__ __launch_bounds__(1024) void arw16896_tscan(int* __restrict__ s) {
    __shared__ int part[4][256];
    __shared__ int colBase[256];
    __shared__ int colTot[256];
    int tid = threadIdx.x;
    int q = tid >> 8, b = tid & 255;
    const int CT = 782;                          // ceil(3125/4)
    int t0 = q * CT, t1 = t0 + CT;
    if (t1 > ARW_NT) t1 = ARW_NT;
    int acc = 0;
    if (b < ARW_NB) for (int t = t0; t < t1; t++) acc += s[ARW_HT + t * ARW_NB + b];
    part[q][b] = acc;
    __syncthreads();
    if (q == 0) colTot[b] = part[0][b] + part[1][b] + part[2][b] + part[3][b];
    __syncthreads();
    if (tid == 0) {
        int a = 0;
        for (int i = 0; i < ARW_NB; i++) { int v = colTot[i]; colBase[i] = a; a += v; }
    }
    __syncthreads();
    if (b < ARW_NB) {
        int run = colBase[b];
        if (q > 0) run += part[0][b];
        if (q > 1) run += part[1][b];
        if (q > 2) run += part[2][b];
        for (int t = t0; t < t1; t++) {
            int v = s[ARW_HT + t * ARW_NB + b];
            s[ARW_BT + t * ARW_NB + b] = run;
            run += v;
        }
    }
}

// ---------- 3. stable partition into buckets (ballot multisplit, no atomics) ----------
__global__ __launch_bounds__(1024) void arw16896_part(const int* __restrict__ row,
                                                      const int* __restrict__ col,
                                                      int* __restrict__ s) {
    __shared__ unsigned W[16 * 256];
    int tid  = threadIdx.x;
    int wave = tid >> 6, lane = tid & 63;
    int e = blockIdx.x * ARW_TILE + tid;
    int r = row[e], cv = col[e];
    int b = r >> 9;
    W[tid] = 0; W[tid + 1024] = 0; W[tid + 2048] = 0; W[tid + 3072] = 0;
    __syncthreads();
    unsigned long long mask = ~0ULL;
    #pragma unroll
    for (int bit = 0; bit < 8; bit++) {
        unsigned long long bal = __ballot((b >> bit) & 1);
        mask &= ((b >> bit) & 1) ? bal : ~bal;
    }
    int rankw = __popcll(mask & ((1ULL << lane) - 1ULL));
    unsigned cnt = (unsigned)__popcll(mask);
    W[wave * 256 + b] = cnt;                    // same value from all matching lanes
    __syncthreads();
    int cross = 0;
    for (int w2 = 0; w2 < 16; w2++) {
        if (w2 >= wave) break;
        cross += (int)W[w2 * 256 + b];
    }
    int base = s[ARW_BT + blockIdx.x * ARW_NB + b];
    s[ARW_P + base + cross + rankw] = ((r & 511) << 17) | cv;   // pack(local_r, col)
}

// ---------- 4. per-bucket LDS sort -> col_s + deg (stable, coalesced out) ----------
__global__ __launch_bounds__(1024) void arw16896_pass2(int* __restrict__ s) {
    extern __shared__ unsigned sm[];
    unsigned* seg  = sm;                        // SEGCAP
    unsigned* hist = sm + ARW_SEGCAP;           // 512
    unsigned* sc   = hist + 512;                // 512
    unsigned* cur  = sc + 512;                  // 512
    int tid = threadIdx.x;
    int b = blockIdx.x;
    int start = s[ARW_BT + b];                  // Bt[t=0][b] = bucket start
    int end   = (b == ARW_NB - 1) ? ARW_N_EDGES : s[ARW_BT + b + 1];
    int cnt = end - start;
    if (cnt > ARW_SEGCAP) cnt = ARW_SEGCAP;     // statistically impossible; OOB guard
    int rows0 = b << 9;
    int nrows = ARW_N_NODES - rows0; if (nrows > 512) nrows = 512;

    if (tid < 512) hist[tid] = 0;
    __syncthreads();
    for (int k = tid; k < cnt; k += 1024)
        atomicAdd(&hist[(unsigned)s[ARW_P + start + k] >> 17], 1u);
    __syncthreads();
    if (tid < 512) sc[tid] = hist[tid];
    __syncthreads();
    for (int off = 1; off < 512; off <<= 1) {   // inclusive scan
        unsigned v = 0;
        if (tid < 512 && tid >= off) v = sc[tid - off];
        __syncthreads();
        if (tid < 512) sc[tid] += v;
        __syncthreads();
    }
    if (tid < 512) {
        cur[tid] = sc[tid] - hist[tid];         // exclusive base
        if (tid < nrows) s[ARW_DEG + rows0 + tid] = (int)hist[tid];
    }
    __syncthreads();
    for (int k = tid; k < cnt; k += 1024) {
        unsigned p = (unsigned)s[ARW_P + start + k];
        unsigned lr = p >> 17;
        unsigned pos = atomicAdd(&cur[lr], 1u);
        seg[pos] = ((unsigned)k << 17) | (p & 0x1FFFFu);   // pack(order, col)
    }
    __syncthreads();
    if (tid < 512) {                            // per-row insertion sort (restores order)
        int base2 = (int)(sc[tid] - hist[tid]);
        int d = (int)hist[tid];
        for (int m = base2 + 1; m < base2 + d; m++) {
            unsigned v = seg[m];
            int j = m - 1;
            while (j >= base2 && seg[j] > v) { seg[j + 1] = seg[j]; j--; }
            seg[j + 1] = v;
        }
    }
    __syncthreads();
    for (int k = tid; k < cnt; k += 1024)
        s[ARW_COLS + start + k] = (int)(seg[k] & 0x1FFFFu);
}

// ---------- 5. rowptr scan over deg (3 kernels, 100k) ----------
__global__ void arw16896_bsum(int* s) {
    __shared__ int sm[256];
    int i = blockIdx.x * 256 + (int)threadIdx.x;
    sm[threadIdx.x] = (i < ARW_N_NODES) ? s[ARW_DEG + i] : 0;
    __syncthreads();
    for (int off = 128; off > 0; off >>= 1) {
        if ((int)threadIdx.x < off) sm[threadIdx.x] += sm[threadIdx.x + off];
        __syncthreads();
    }
    if (threadIdx.x == 0) s[ARW_BSUM + blockIdx.x] = sm[0];
}
__global__ void arw16896_bscan(int* s) {
    if (blockIdx.x == 0 && threadIdx.x == 0) {
        int acc = 0;
        for (int b = 0; b < ARW_NBLK; b++) { int v = s[ARW_BSUM + b]; s[ARW_BSUM + b] = acc; acc += v; }
    }
}
__global__ void arw16896_scan(int* s) {
    __shared__ int sm[256];
    int i = blockIdx.x * 256 + (int)threadIdx.x;
    sm[threadIdx.x] = (i < ARW_N_NODES) ? s[ARW_DEG + i] : 0;
    __syncthreads();
    for (int off = 1; off < 256; off <<= 1) {
        int x = 0;
        if ((int)threadIdx.x >= off) x = sm[threadIdx.x - off];
        __syncthreads();
        sm[threadIdx.x] += x;
        __syncthreads();
    }
    if (i < ARW_N_NODES) s[ARW_RP + i + 1] = sm[threadIdx.x] + s[ARW_BSUM + blockIdx.x];
    if (i == 0) s[ARW_RP] = 0;
}

// ---------- 6. walks: float4 rand loads, LDS-staged coalesced target stores ----------
__global__ __launch_bounds__(256) void arw16896_walk(const float* __restrict__ ru,
                                                     const int* __restrict__ s,
                                                     float* __restrict__ o) {
    __shared__ float tg[256 * ARW_LOUT];
    int tid = threadIdx.x;
    int w = blockIdx.x * 256 + tid;
    if (w < ARW_N_WALKERS) {
        const float4* rp = (const float4*)(ru + (size_t)w * 8);
        float4 ra = rp[0], rb = rp[1];
        float uu[8] = {ra.x, ra.y, ra.z, ra.w, rb.x, rb.y, rb.z, rb.w};
        int cur = w % ARW_N_NODES;
        #pragma unroll
        for (int t = 0; t < ARW_WLEN; t++) {
            int d = s[ARW_DEG + cur];
            if (d > 0) {
                int off = (int)(uu[t] * (float)d);   // f32 mul + trunc == reference
                if (off > d - 1) off = d - 1;
                cur = s[ARW_COLS + s[ARW_RP + cur] + off];
            }
            if (t >= 1) tg[tid * ARW_LOUT + (t - 1)] = (float)cur;
        }
    }
    __syncthreads();
    int blkW = ARW_N_WALKERS - blockIdx.x * 256;
    if (blkW > 256) blkW = 256;
    int valid = blkW * ARW_LOUT;
    int base = ARW_ROW_LEN + ARW_N_EDGES + blockIdx.x * 256 * ARW_LOUT;
    for (int j = tid; j < valid; j += 256) o[base + j] = tg[j];
}

// ---------- 7. assembly: originals (vectorized) ----------
__global__ void arw16896_asmo(const int* __restrict__ ei, const float* __restrict__ wgt,
                              float* __restrict__ o) {
    int i4 = blockIdx.x * blockDim.x + threadIdx.x;   // 800k threads, 4 elems each
    if (i4 >= ARW_N_EDGES / 4) return;
    int4 r0 = ((const int4*)ei)[i4];
    int4 r1 = ((const int4*)(ei + ARW_N_EDGES))[i4];
    float4 wv = ((const float4*)wgt)[i4];
    float4 f0 = make_float4((float)r0.x, (float)r0.y, (float)r0.z, (float)r0.w);
    float4 f1 = make_float4((float)r1.x, (float)r1.y, (float)r1.z, (float)r1.w);
    ((float4*)o)[i4] = f0;
    ((float4*)(o + ARW_ROW_LEN))[i4] = f1;
    ((float4*)(o + 2 * ARW_ROW_LEN))[i4] = wv;
}

// ---------- 8. assembly: roots + ones (vectorized stores) ----------
__global__ void arw16896_asmt(float* __restrict__ o) {
    int i4 = blockIdx.x * blockDim.x + threadIdx.x;   // 700k threads, 4 elems each
    if (i4 >= (ARW_N_WALKERS * ARW_LOUT) / 4) return;
    int i = i4 * 4;
    float4 r;
    r.x = (float)(((i    ) / ARW_LOUT) % ARW_N_NODES);
    r.y = (float)(((i + 1) / ARW_LOUT) % ARW_N_NODES);
    r.z = (float)(((i + 2) / ARW_LOUT) % ARW_N_NODES);
    r.w = (float)(((i + 3) / ARW_LOUT) % ARW_N_NODES);
    ((float4*)(o + ARW_N_EDGES))[i4] = r;
    ((float4*)(o + 2 * ARW_ROW_LEN + ARW_N_EDGES))[i4] = make_float4(1.f, 1.f, 1.f, 1.f);
}

extern "C" void kernel_launch(void* const* d_in, const int* in_sizes, int n_in,
                              void* d_out, int out_size, void* d_ws, size_t ws_size,
                              hipStream_t stream) {
    const int*   ei  = (const int*)d_in[0];
    const float* wgt = (const float*)d_in[1];
    const float* ru  = (const float*)d_in[2];
    int*   s = (int*)d_out;
    float* o = (float*)d_out;
    const int* row = ei;
    const int* col = ei + ARW_N_EDGES;

    size_t p2lds = (size_t)(ARW_SEGCAP + 3 * 512) * sizeof(unsigned);  // ~79.9 KB

    arw16896_thist <<<ARW_NT, 1024, 0, stream>>>(row, s);
    arw16896_tscan <<<1, 1024, 0, stream>>>(s);
    arw16896_part  <<<ARW_NT, 1024, 0, stream>>>(row, col, s);
    arw16896_pass2 <<<ARW_NB, 1024, p2lds, stream>>>(s);
    arw16896_bsum  <<<ARW_NBLK, 256, 0, stream>>>(s);
    arw16896_bscan <<<1, 64, 0, stream>>>(s);
    arw16896_scan  <<<ARW_NBLK, 256, 0, stream>>>(s);
    arw16896_walk  <<<(ARW_N_WALKERS + 255) / 256, 256, 0, stream>>>(ru, s, o);
    arw16896_asmo  <<<(ARW_N_EDGES / 4 + 255) / 256, 256, 0, stream>>>(ei, wgt, o);
    arw16896_asmt  <<<((ARW_N_WALKERS * ARW_LOUT) / 4 + 255) / 256, 256, 0, stream>>>(o);
}

// Round 8
// 289.708 us; speedup vs baseline: 5.5068x; 1.7938x over previous
//
#include <hip/hip_runtime.h>

// Problem constants
#define ARW_N_NODES   100000
#define ARW_N_EDGES   3200000
#define ARW_N_WALKERS 400000
#define ARW_WLEN      8
#define ARW_LOUT      7
#define ARW_ROW_LEN   6000000           // N_EDGES + N_WALKERS*LOUT
#define ARW_OUT_ELEMS 18000000          // float32 output elements

// Sort geometry: 196 buckets of 512 rows (b = r>>9); 3125 tiles of 1024 edges.
#define ARW_NB    196
#define ARW_NT    3125
#define ARW_TP    3136                 // padded row stride for Ht/Bt (t-contiguous)
#define ARW_TILE  1024
#define ARW_SEGCAP 18432               // LDS cap per bucket (mean 16384, sigma ~127)

// Scratch inside d_out (18M floats = 72MB), int32 view; staged lifetimes:
//   Ht  @ [0, 614656)          histograms Ht[b][t] = HT + b*TP + t
//   Bt  @ [700000, 1314656)    scan bases Bt[b][t]; Bt[b][0] = bucket start
//   tot @ [1350000, +196)      per-bucket totals
//   cb  @ [1360000, +196)      bucket exclusive bases
//   deg @ [1400000, 1500000)
//   rowptr @ [1500000, 1600001)
//   bsum@ [1610000, +391)
//   P   @ [6000000, 9200000)   packed partition (row1-orig region, dead after pass2)
//   col_s @ [12000000, 15200000) (weights region; assemble overwrites last)
// walk writes float targets @ [9200000, 12000000).
#define ARW_HT    0
#define ARW_BT    700000
#define ARW_TOT   1350000
#define ARW_CB    1360000
#define ARW_DEG   1400000
#define ARW_RP    1500000
#define ARW_BSUM  1610000
#define ARW_P     6000000
#define ARW_COLS  12000000
#define ARW_NBLK  391                  // ceil(N_NODES/256) for rowptr scan

__global__ void AddRandomWalkEdge_16896401342869_kernel() {}

// ---------- 1. tile histogram over 196 buckets (LDS atomics only) ----------
__global__ __launch_bounds__(1024) void arw16896_thist(const int* __restrict__ row,
                                                       int* __restrict__ s) {
    __shared__ int h[256];
    int tid = threadIdx.x;
    if (tid < 256) h[tid] = 0;
    __syncthreads();
    int e = blockIdx.x * ARW_TILE + tid;
    atomicAdd(&h[row[e] >> 9], 1);
    __syncthreads();
    if (tid < ARW_NB) s[ARW_HT + tid * ARW_TP + blockIdx.x] = h[tid];  // transposed
}

// ---------- 2a. per-bucket totals (196 blocks, coalesced row sums) ----------
__global__ __launch_bounds__(256) void arw16896_btot(int* __restrict__ s) {
    __shared__ int sm[256];
    int b = blockIdx.x, tid = threadIdx.x;
    int acc = 0;
    for (int t = tid; t < ARW_NT; t += 256) acc += s[ARW_HT + b * ARW_TP + t];
    sm[tid] = acc;
    __syncthreads();
    for (int off = 128; off > 0; off >>= 1) {
        if (tid < off) sm[tid] += sm[tid + off];
        __syncthreads();
    }
    if (tid == 0) s[ARW_TOT + b] = sm[0];
}

// ---------- 2b. exclusive scan of 196 bucket totals (1 small block) ----------
__global__ __launch_bounds__(256) void arw16896_bbase(int* __restrict__ s) {
    __shared__ int sm[256];
    int tid = threadIdx.x;
    int v = (tid < ARW_NB) ? s[ARW_TOT + tid] : 0;
    sm[tid] = v;
    __syncthreads();
    for (int off = 1; off < 256; off <<= 1) {
        int x = 0;
        if (tid >= off) x = sm[tid - off];
        __syncthreads();
        sm[tid] += x;
        __syncthreads();
    }
    if (tid < ARW_NB) s[ARW_CB + tid] = sm[tid] - v;   // exclusive
}

// ---------- 2c. per-bucket chunked exclusive scan -> Bt[b][t] ----------
__global__ __launch_bounds__(256) void arw16896_bscan2(int* __restrict__ s) {
    __shared__ int sm[256];
    int b = blockIdx.x, tid = threadIdx.x;
    int carry = s[ARW_CB + b];
    for (int c0 = 0; c0 < ARW_NT; c0 += 256) {
        int t = c0 + tid;
        int v = (t < ARW_NT) ? s[ARW_HT + b * ARW_TP + t] : 0;
        sm[tid] = v;
        __syncthreads();
        for (int off = 1; off < 256; off <<= 1) {       // inclusive scan
            int x = 0;
            if (tid >= off) x = sm[tid - off];
            __syncthreads();
            sm[tid] += x;
            __syncthreads();
        }
        if (t < ARW_NT) s[ARW_BT + b * ARW_TP + t] = carry + sm[tid] - v;  // exclusive
        int tot = sm[255];
        __syncthreads();                                 // protect sm before next chunk
        carry += tot;
    }
}

// ---------- 3. stable partition into buckets (ballot multisplit, no atomics) ----------
__global__ __launch_bounds__(1024) void arw16896_part(const int* __restrict__ row,
                                                      const int* __restrict__ col,
                                                      int* __restrict__ s) {
    __shared__ unsigned W[16 * 256];
    int tid  = threadIdx.x;
    int wave = tid >> 6, lane = tid & 63;
    int e = blockIdx.x * ARW_TILE + tid;
    int r = row[e], cv = col[e];
    int b = r >> 9;
    W[tid] = 0; W[tid + 1024] = 0; W[tid + 2048] = 0; W[tid + 3072] = 0;
    __syncthreads();
    unsigned long long mask = ~0ULL;
    #pragma unroll
    for (int bit = 0; bit < 8; bit++) {
        unsigned long long bal = __ballot((b >> bit) & 1);
        mask &= ((b >> bit) & 1) ? bal : ~bal;
    }
    int rankw = __popcll(mask & ((1ULL << lane) - 1ULL));
    unsigned cnt = (unsigned)__popcll(mask);
    W[wave * 256 + b] = cnt;                    // same value from all matching lanes
    __syncthreads();
    int cross = 0;
    for (int w2 = 0; w2 < 16; w2++) {
        if (w2 >= wave) break;
        cross += (int)W[w2 * 256 + b];
    }
    int base = s[ARW_BT + b * ARW_TP + blockIdx.x];      // transposed lookup
    s[ARW_P + base + cross + rankw] = ((r & 511) << 17) | cv;   // pack(local_r, col)
}

// ---------- 4. per-bucket LDS sort -> col_s + deg (stable, coalesced out) ----------
__global__ __launch_bounds__(1024) void arw16896_pass2(int* __restrict__ s) {
    extern __shared__ unsigned sm[];
    unsigned* seg  = sm;                        // SEGCAP
    unsigned* hist = sm + ARW_SEGCAP;           // 512
    unsigned* sc   = hist + 512;                // 512
    unsigned* cur  = sc + 512;                  // 512
    int tid = threadIdx.x;
    int b = blockIdx.x;
    int start = s[ARW_BT + b * ARW_TP];                        // bucket start
    int end   = (b == ARW_NB - 1) ? ARW_N_EDGES : s[ARW_BT + (b + 1) * ARW_TP];
    int cnt = end - start;
    if (cnt > ARW_SEGCAP) cnt = ARW_SEGCAP;     // statistically impossible; OOB guard
    int rows0 = b << 9;
    int nrows = ARW_N_NODES - rows0; if (nrows > 512) nrows = 512;

    if (tid < 512) hist[tid] = 0;
    __syncthreads();
    for (int k = tid; k < cnt; k += 1024)
        atomicAdd(&hist[(unsigned)s[ARW_P + start + k] >> 17], 1u);
    __syncthreads();
    if (tid < 512) sc[tid] = hist[tid];
    __syncthreads();
    for (int off = 1; off < 512; off <<= 1) {   // inclusive scan
        unsigned v = 0;
        if (tid < 512 && tid >= off) v = sc[tid - off];
        __syncthreads();
        if (tid < 512) sc[tid] += v;
        __syncthreads();
    }
    if (tid < 512) {
        cur[tid] = sc[tid] - hist[tid];         // exclusive base
        if (tid < nrows) s[ARW_DEG + rows0 + tid] = (int)hist[tid];
    }
    __syncthreads();
    for (int k = tid; k < cnt; k += 1024) {
        unsigned p = (unsigned)s[ARW_P + start + k];
        unsigned lr = p >> 17;
        unsigned pos = atomicAdd(&cur[lr], 1u);
        seg[pos] = ((unsigned)k << 17) | (p & 0x1FFFFu);   // pack(order, col)
    }
    __syncthreads();
    if (tid < 512) {                            // per-row insertion sort (restores order)
        int base2 = (int)(sc[tid] - hist[tid]);
        int d = (int)hist[tid];
        for (int m = base2 + 1; m < base2 + d; m++) {
            unsigned v = seg[m];
            int j = m - 1;
            while (j >= base2 && seg[j] > v) { seg[j + 1] = seg[j]; j--; }
            seg[j + 1] = v;
        }
    }
    __syncthreads();
    for (int k = tid; k < cnt; k += 1024)
        s[ARW_COLS + start + k] = (int)(seg[k] & 0x1FFFFu);
}

// ---------- 5. rowptr scan over deg (3 kernels, 100k) ----------
__global__ void arw16896_bsum(int* s) {
    __shared__ int sm[256];
    int i = blockIdx.x * 256 + (int)threadIdx.x;
    sm[threadIdx.x] = (i < ARW_N_NODES) ? s[ARW_DEG + i] : 0;
    __syncthreads();
    for (int off = 128; off > 0; off >>= 1) {
        if ((int)threadIdx.x < off) sm[threadIdx.x] += sm[threadIdx.x + off];
        __syncthreads();
    }
    if (threadIdx.x == 0) s[ARW_BSUM + blockIdx.x] = sm[0];
}
__global__ void arw16896_bscan(int* s) {
    if (blockIdx.x == 0 && threadIdx.x == 0) {
        int acc = 0;
        for (int b = 0; b < ARW_NBLK; b++) { int v = s[ARW_BSUM + b]; s[ARW_BSUM + b] = acc; acc += v; }
    }
}
__global__ void arw16896_scan(int* s) {
    __shared__ int sm[256];
    int i = blockIdx.x * 256 + (int)threadIdx.x;
    sm[threadIdx.x] = (i < ARW_N_NODES) ? s[ARW_DEG + i] : 0;
    __syncthreads();
    for (int off = 1; off < 256; off <<= 1) {
        int x = 0;
        if ((int)threadIdx.x >= off) x = sm[threadIdx.x - off];
        __syncthreads();
        sm[threadIdx.x] += x;
        __syncthreads();
    }
    if (i < ARW_N_NODES) s[ARW_RP + i + 1] = sm[threadIdx.x] + s[ARW_BSUM + blockIdx.x];
    if (i == 0) s[ARW_RP] = 0;
}

// ---------- 6. walks: float4 rand loads, LDS-staged coalesced target stores ----------
__global__ __launch_bounds__(256) void arw16896_walk(const float* __restrict__ ru,
                                                     const int* __restrict__ s,
                                                     float* __restrict__ o) {
    __shared__ float tg[256 * ARW_LOUT];
    int tid = threadIdx.x;
    int w = blockIdx.x * 256 + tid;
    if (w < ARW_N_WALKERS) {
        const float4* rp = (const float4*)(ru + (size_t)w * 8);
        float4 ra = rp[0], rb = rp[1];
        float uu[8] = {ra.x, ra.y, ra.z, ra.w, rb.x, rb.y, rb.z, rb.w};
        int cur = w % ARW_N_NODES;
        #pragma unroll
        for (int t = 0; t < ARW_WLEN; t++) {
            int d = s[ARW_DEG + cur];
            if (d > 0) {
                int off = (int)(uu[t] * (float)d);   // f32 mul + trunc == reference
                if (off > d - 1) off = d - 1;
                cur = s[ARW_COLS + s[ARW_RP + cur] + off];
            }
            if (t >= 1) tg[tid * ARW_LOUT + (t - 1)] = (float)cur;
        }
    }
    __syncthreads();
    int blkW = ARW_N_WALKERS - blockIdx.x * 256;
    if (blkW > 256) blkW = 256;
    int valid = blkW * ARW_LOUT;
    int base = ARW_ROW_LEN + ARW_N_EDGES + blockIdx.x * 256 * ARW_LOUT;
    for (int j = tid; j < valid; j += 256) o[base + j] = tg[j];
}

// ---------- 7. assembly: originals (vectorized) ----------
__global__ void arw16896_asmo(const int* __restrict__ ei, const float* __restrict__ wgt,
                              float* __restrict__ o) {
    int i4 = blockIdx.x * blockDim.x + threadIdx.x;   // 800k threads, 4 elems each
    if (i4 >= ARW_N_EDGES / 4) return;
    int4 r0 = ((const int4*)ei)[i4];
    int4 r1 = ((const int4*)(ei + ARW_N_EDGES))[i4];
    float4 wv = ((const float4*)wgt)[i4];
    float4 f0 = make_float4((float)r0.x, (float)r0.y, (float)r0.z, (float)r0.w);
    float4 f1 = make_float4((float)r1.x, (float)r1.y, (float)r1.z, (float)r1.w);
    ((float4*)o)[i4] = f0;
    ((float4*)(o + ARW_ROW_LEN))[i4] = f1;
    ((float4*)(o + 2 * ARW_ROW_LEN))[i4] = wv;
}

// ---------- 8. assembly: roots + ones (vectorized stores) ----------
__global__ void arw16896_asmt(float* __restrict__ o) {
    int i4 = blockIdx.x * blockDim.x + threadIdx.x;   // 700k threads, 4 elems each
    if (i4 >= (ARW_N_WALKERS * ARW_LOUT) / 4) return;
    int i = i4 * 4;
    float4 r;
    r.x = (float)(((i    ) / ARW_LOUT) % ARW_N_NODES);
    r.y = (float)(((i + 1) / ARW_LOUT) % ARW_N_NODES);
    r.z = (float)(((i + 2) / ARW_LOUT) % ARW_N_NODES);
    r.w = (float)(((i + 3) / ARW_LOUT) % ARW_N_NODES);
    ((float4*)(o + ARW_N_EDGES))[i4] = r;
    ((float4*)(o + 2 * ARW_ROW_LEN + ARW_N_EDGES))[i4] = make_float4(1.f, 1.f, 1.f, 1.f);
}

extern "C" void kernel_launch(void* const* d_in, const int* in_sizes, int n_in,
                              void* d_out, int out_size, void* d_ws, size_t ws_size,
                              hipStream_t stream) {
    const int*   ei  = (const int*)d_in[0];
    const float* wgt = (const float*)d_in[1];
    const float* ru  = (const float*)d_in[2];
    int*   s = (int*)d_out;
    float* o = (float*)d_out;
    const int* row = ei;
    const int* col = ei + ARW_N_EDGES;

    size_t p2lds = (size_t)(ARW_SEGCAP + 3 * 512) * sizeof(unsigned);  // ~79.9 KB

    arw16896_thist <<<ARW_NT, 1024, 0, stream>>>(row, s);
    arw16896_btot  <<<ARW_NB, 256, 0, stream>>>(s);
    arw16896_bbase <<<1, 256, 0, stream>>>(s);
    arw16896_bscan2<<<ARW_NB, 256, 0, stream>>>(s);
    arw16896_part  <<<ARW_NT, 1024, 0, stream>>>(row, col, s);
    arw16896_pass2 <<<ARW_NB, 1024, p2lds, stream>>>(s);
    arw16896_bsum  <<<ARW_NBLK, 256, 0, stream>>>(s);
    arw16896_bscan <<<1, 64, 0, stream>>>(s);
    arw16896_scan  <<<ARW_NBLK, 256, 0, stream>>>(s);
    arw16896_walk  <<<(ARW_N_WALKERS + 255) / 256, 256, 0, stream>>>(ru, s, o);
    arw16896_asmo  <<<(ARW_N_EDGES / 4 + 255) / 256, 256, 0, stream>>>(ei, wgt, o);
    arw16896_asmt  <<<((ARW_N_WALKERS * ARW_LOUT) / 4 + 255) / 256, 256, 0, stream>>>(o);
}

// Round 9
// 262.389 us; speedup vs baseline: 6.0801x; 1.1041x over previous
//
#include <hip/hip_runtime.h>

// Problem constants
#define ARW_N_NODES   100000
#define ARW_N_EDGES   3200000
#define ARW_N_WALKERS 400000
#define ARW_WLEN      8
#define ARW_LOUT      7
#define ARW_ROW_LEN   6000000           // N_EDGES + N_WALKERS*LOUT
#define ARW_OUT_ELEMS 18000000          // float32 output elements

// Sort geometry: 196 buckets of 512 rows (b = r>>9); 3125 tiles of 1024 edges.
#define ARW_NB    196
#define ARW_NT    3125
#define ARW_TP    3136                 // padded row stride for Ht/Bt (t-contiguous)
#define ARW_TILE  1024

// Scratch inside d_out (18M floats = 72MB), int32 view; staged lifetimes:
//   Ht  @ [0, 614656)          histograms Ht[b][t] = HT + b*TP + t
//   Bt  @ [700000, 1314656)    scan bases Bt[b][t]; Bt[b][0] = bucket start
//   tot @ [1350000, +196)      per-bucket totals
//   cb  @ [1360000, +196)      bucket exclusive bases
//   deg @ [1400000, 1500000)   written by pass2
//   rowptr @ [1500000, 1600000) written by pass2
//   P   @ [6000000, 9200000)   packed partition (row1-orig region, dead after pass2)
//   col_s @ [12000000, 15200000) (weights region; asm overwrites last)
// walk writes float targets @ [9200000, 12000000). asm (last) overwrites all scratch.
#define ARW_HT    0
#define ARW_BT    700000
#define ARW_TOT   1350000
#define ARW_CB    1360000
#define ARW_DEG   1400000
#define ARW_RP    1500000
#define ARW_P     6000000
#define ARW_COLS  12000000

__global__ void AddRandomWalkEdge_16896401342869_kernel() {}

// ---------- 1. tile histogram over 196 buckets (LDS atomics, transposed out) ----------
__global__ __launch_bounds__(1024) void arw16896_thist(const int* __restrict__ row,
                                                       int* __restrict__ s) {
    __shared__ int h[256];
    int tid = threadIdx.x;
    if (tid < 256) h[tid] = 0;
    __syncthreads();
    atomicAdd(&h[row[blockIdx.x * ARW_TILE + tid] >> 9], 1);
    __syncthreads();
    if (tid < ARW_NB) s[ARW_HT + tid * ARW_TP + blockIdx.x] = h[tid];
}

// ---------- 2a. per-bucket totals (196 blocks, 1024 thr, shuffle reduce) ----------
__global__ __launch_bounds__(1024) void arw16896_btot(int* __restrict__ s) {
    __shared__ int wsum[16];
    int b = blockIdx.x, tid = threadIdx.x, lane = tid & 63, wid = tid >> 6;
    int acc = 0;
    for (int t = tid; t < ARW_NT; t += 1024) acc += s[ARW_HT + b * ARW_TP + t];
    #pragma unroll
    for (int off = 32; off > 0; off >>= 1) acc += __shfl_down(acc, off, 64);
    if (lane == 0) wsum[wid] = acc;
    __syncthreads();
    if (tid == 0) {
        int a = 0;
        #pragma unroll
        for (int w = 0; w < 16; w++) a += wsum[w];
        s[ARW_TOT + b] = a;
    }
}

// ---------- 2b. exclusive scan of 196 bucket totals (1 block) ----------
__global__ __launch_bounds__(256) void arw16896_bbase(int* __restrict__ s) {
    __shared__ int sm[256];
    int tid = threadIdx.x;
    int v = (tid < ARW_NB) ? s[ARW_TOT + tid] : 0;
    sm[tid] = v;
    __syncthreads();
    for (int off = 1; off < 256; off <<= 1) {
        int x = 0;
        if (tid >= off) x = sm[tid - off];
        __syncthreads();
        sm[tid] += x;
        __syncthreads();
    }
    if (tid < ARW_NB) s[ARW_CB + tid] = sm[tid] - v;
}

// ---------- 2c. per-bucket chunked exclusive scan -> Bt[b][t] (shuffle) ----------
__global__ __launch_bounds__(1024) void arw16896_bscan2(int* __restrict__ s) {
    __shared__ int wsum[16];
    int b = blockIdx.x, tid = threadIdx.x, lane = tid & 63, wid = tid >> 6;
    int carry = s[ARW_CB + b];
    for (int c0 = 0; c0 < ARW_NT; c0 += 1024) {
        int t = c0 + tid;
        int v = (t < ARW_NT) ? s[ARW_HT + b * ARW_TP + t] : 0;
        int sv = v;
        #pragma unroll
        for (int off = 1; off < 64; off <<= 1) {
            int x = __shfl_up(sv, off, 64);
            if (lane >= off) sv += x;
        }
        if (lane == 63) wsum[wid] = sv;
        __syncthreads();
        int pre = 0, tot = 0;
        #pragma unroll
        for (int w = 0; w < 16; w++) {
            int x = wsum[w];
            if (w < wid) pre += x;
            tot += x;
        }
        if (t < ARW_NT) s[ARW_BT + b * ARW_TP + t] = carry + pre + sv - v;
        carry += tot;
        __syncthreads();
    }
}

// ---------- 3. stable partition into buckets (ballot multisplit, no atomics) ----------
__global__ __launch_bounds__(1024) void arw16896_part(const int* __restrict__ row,
                                                      const int* __restrict__ col,
                                                      int* __restrict__ s) {
    __shared__ unsigned W[16 * 256];
    int tid  = threadIdx.x;
    int wave = tid >> 6, lane = tid & 63;
    int e = blockIdx.x * ARW_TILE + tid;
    int r = row[e], cv = col[e];
    int b = r >> 9;
    W[tid] = 0; W[tid + 1024] = 0; W[tid + 2048] = 0; W[tid + 3072] = 0;
    __syncthreads();
    unsigned long long mask = ~0ULL;
    #pragma unroll
    for (int bit = 0; bit < 8; bit++) {
        unsigned long long bal = __ballot((b >> bit) & 1);
        mask &= ((b >> bit) & 1) ? bal : ~bal;
    }
    int rankw = __popcll(mask & ((1ULL << lane) - 1ULL));
    W[wave * 256 + b] = (unsigned)__popcll(mask);
    __syncthreads();
    int cross = 0;
    for (int w2 = 0; w2 < 16; w2++) {
        if (w2 >= wave) break;
        cross += (int)W[w2 * 256 + b];
    }
    int base = s[ARW_BT + b * ARW_TP + blockIdx.x];
    s[ARW_P + base + cross + rankw] = ((r & 511) << 17) | cv;   // pack(local_r, col)
}

// ---------- 4. per-bucket stable scatter -> col_s + deg + rowptr ----------
// Pass A: 512-bin histogram + scan (also emits deg, rowptr).
// Pass B: chunked 9-bit ballot multisplit: in-wave rank + cross-wave LDS table
//         + running per-row count -> stable global position. No sorting.
__global__ __launch_bounds__(1024) void arw16896_pass2(int* __restrict__ s) {
    __shared__ unsigned W[16 * 512];          // 32 KB
    __shared__ int hist[512], pref[512], runc[512];
    int tid = threadIdx.x, lane = tid & 63, wave = tid >> 6;
    int b = blockIdx.x;
    int start = s[ARW_BT + b * ARW_TP];
    int end   = (b == ARW_NB - 1) ? ARW_N_EDGES : s[ARW_BT + (b + 1) * ARW_TP];
    int cnt = end - start;
    int rows0 = b << 9;
    int nrows = ARW_N_NODES - rows0; if (nrows > 512) nrows = 512;

    // Pass A: histogram
    if (tid < 512) hist[tid] = 0;
    __syncthreads();
    for (int k = tid; k < cnt; k += 1024)
        atomicAdd(&hist[(unsigned)s[ARW_P + start + k] >> 17], 1);
    __syncthreads();
    if (tid < 512) pref[tid] = hist[tid];
    __syncthreads();
    for (int off = 1; off < 512; off <<= 1) {     // inclusive scan of hist
        int x = 0;
        if (tid < 512 && tid >= off) x = pref[tid - off];
        __syncthreads();
        if (tid < 512) pref[tid] += x;
        __syncthreads();
    }
    if (tid < 512) runc[tid] = 0;
    if (tid < nrows) {
        s[ARW_DEG + rows0 + tid] = hist[tid];
        s[ARW_RP  + rows0 + tid] = start + pref[tid] - hist[tid];
    }
    __syncthreads();

    // Pass B: stable scatter
    for (int c0 = 0; c0 < cnt; c0 += 1024) {
        int k = c0 + tid;
        int valid = (k < cnt) ? 1 : 0;
        unsigned p = valid ? (unsigned)s[ARW_P + start + k] : 0u;
        unsigned lr = p >> 17;                     // 9 bits
        #pragma unroll
        for (int j = 0; j < 8; j++) W[tid + j * 1024] = 0;
        __syncthreads();
        unsigned long long mask = ~0ULL;
        #pragma unroll
        for (int bit = 0; bit < 9; bit++) {
            unsigned long long bal = __ballot((lr >> bit) & 1u);
            mask &= ((lr >> bit) & 1u) ? bal : ~bal;
        }
        mask &= __ballot(valid);
        int rankw = __popcll(mask & ((1ULL << lane) - 1ULL));
        if (valid) W[wave * 512 + lr] = (unsigned)__popcll(mask);
        __syncthreads();
        if (valid) {
            int cross = 0;
            for (int w2 = 0; w2 < 16; w2++) {
                if (w2 >= wave) break;
                cross += (int)W[w2 * 512 + lr];
            }
            int pos = start + (pref[lr] - hist[lr]) + runc[lr] + cross + rankw;
            s[ARW_COLS + pos] = (int)(p & 0x1FFFFu);
        }
        __syncthreads();
        if (tid < 512) {
            int a = 0;
            #pragma unroll
            for (int w = 0; w < 16; w++) a += (int)W[w * 512 + tid];
            runc[tid] += a;
        }
        __syncthreads();
    }
}

// ---------- 5. walks: float4 rand loads, LDS-staged coalesced target stores ----------
__global__ __launch_bounds__(256) void arw16896_walk(const float* __restrict__ ru,
                                                     const int* __restrict__ s,
                                                     float* __restrict__ o) {
    __shared__ float tg[256 * ARW_LOUT];
    int tid = threadIdx.x;
    int w = blockIdx.x * 256 + tid;
    if (w < ARW_N_WALKERS) {
        const float4* rp = (const float4*)(ru + (size_t)w * 8);
        float4 ra = rp[0], rb = rp[1];
        float uu[8] = {ra.x, ra.y, ra.z, ra.w, rb.x, rb.y, rb.z, rb.w};
        int cur = w % ARW_N_NODES;
        #pragma unroll
        for (int t = 0; t < ARW_WLEN; t++) {
            int d = s[ARW_DEG + cur];
            if (d > 0) {
                int off = (int)(uu[t] * (float)d);   // f32 mul + trunc == reference
                if (off > d - 1) off = d - 1;
                cur = s[ARW_COLS + s[ARW_RP + cur] + off];
            }
            if (t >= 1) tg[tid * ARW_LOUT + (t - 1)] = (float)cur;
        }
    }
    __syncthreads();
    int blkW = ARW_N_WALKERS - blockIdx.x * 256;
    if (blkW > 256) blkW = 256;
    int valid = blkW * ARW_LOUT;
    int base = ARW_ROW_LEN + ARW_N_EDGES + blockIdx.x * 256 * ARW_LOUT;
    for (int j = tid; j < valid; j += 256) o[base + j] = tg[j];
}

// ---------- 6. merged assembly: originals + roots + ones (vectorized) ----------
__global__ __launch_bounds__(256) void arw16896_asm(const int* __restrict__ ei,
                                                    const float* __restrict__ wgt,
                                                    float* __restrict__ o) {
    int i4 = blockIdx.x * blockDim.x + threadIdx.x;
    if (i4 < ARW_N_EDGES / 4) {
        int4 r0 = ((const int4*)ei)[i4];
        int4 r1 = ((const int4*)(ei + ARW_N_EDGES))[i4];
        float4 wv = ((const float4*)wgt)[i4];
        ((float4*)o)[i4] = make_float4((float)r0.x, (float)r0.y, (float)r0.z, (float)r0.w);
        ((float4*)(o + ARW_ROW_LEN))[i4] =
            make_float4((float)r1.x, (float)r1.y, (float)r1.z, (float)r1.w);
        ((float4*)(o + 2 * ARW_ROW_LEN))[i4] = wv;
    }
    if (i4 < (ARW_N_WALKERS * ARW_LOUT) / 4) {
        int i = i4 * 4;
        float4 r;
        r.x = (float)(((i    ) / ARW_LOUT) % ARW_N_NODES);
        r.y = (float)(((i + 1) / ARW_LOUT) % ARW_N_NODES);
        r.z = (float)(((i + 2) / ARW_LOUT) % ARW_N_NODES);
        r.w = (float)(((i + 3) / ARW_LOUT) % ARW_N_NODES);
        ((float4*)(o + ARW_N_EDGES))[i4] = r;
        ((float4*)(o + 2 * ARW_ROW_LEN + ARW_N_EDGES))[i4] = make_float4(1.f, 1.f, 1.f, 1.f);
    }
}

extern "C" void kernel_launch(void* const* d_in, const int* in_sizes, int n_in,
                              void* d_out, int out_size, void* d_ws, size_t ws_size,
                              hipStream_t stream) {
    const int*   ei  = (const int*)d_in[0];
    const float* wgt = (const float*)d_in[1];
    const float* ru  = (const float*)d_in[2];
    int*   s = (int*)d_out;
    float* o = (float*)d_out;
    const int* row = ei;
    const int* col = ei + ARW_N_EDGES;

    arw16896_thist <<<ARW_NT, 1024, 0, stream>>>(row, s);
    arw16896_btot  <<<ARW_NB, 1024, 0, stream>>>(s);
    arw16896_bbase <<<1, 256, 0, stream>>>(s);
    arw16896_bscan2<<<ARW_NB, 1024, 0, stream>>>(s);
    arw16896_part  <<<ARW_NT, 1024, 0, stream>>>(row, col, s);
    arw16896_pass2 <<<ARW_NB, 1024, 0, stream>>>(s);
    arw16896_walk  <<<(ARW_N_WALKERS + 255) / 256, 256, 0, stream>>>(ru, s, o);
    arw16896_asm   <<<(ARW_N_EDGES / 4 + 255) / 256, 256, 0, stream>>>(ei, wgt, o);
}